// Round 6
// baseline (181.345 us; speedup 1.0000x reference)
//
#include <hip/hip_runtime.h>
#include <math.h>

#define HW     9216
#define KJ     17
#define BATCH  128
#define TOPK   8
#define NROW   (BATCH * KJ)      // 2176
#define NBLK   (NROW / 2)        // 1088 persistent 2-row blocks
#define QF4    576               // float4 per quarter-row (2304 floats)

// R6: barrier-free persistent blocks. Evidence: R3/R5 replay dispatches with
// inputs fully L3-resident (hbm_bytes 70-212 KB) ran the SAME 60us as the
// 78MB-HBM-fetch dispatches -> backing store irrelevant; limiter is the
// device-wide L2-miss read path (queueing-dominated). m13 copy demonstrated
// ~3.15 TB/s read on that path; we sit at 2.65 (84%). Residual suspects,
// common to ALL prior variants: one-row block churn, per-block __syncthreads
// (HIP barrier = forced s_waitcnt vmcnt(0) drain), lockstep retire. This
// version: 1088 blocks x 2 rows, one wave per quarter-row, per-wave partials
// to global (NO barrier in k1), one 4-deep load ring flowing continuously
// across the row boundary. k2 sums 4 wave-partials per row.
__global__ __launch_bounds__(256, 4) void per_joint_partial(
    const float* __restrict__ outp, const float* __restrict__ tgt,
    float* __restrict__ pw)
{
    const int b    = blockIdx.x;
    const int r0   = b;                  // first row
    const int r1   = b + NBLK;           // second row
    const int tid  = threadIdx.x;
    const int lane = tid & 63;
    const int wave = tid >> 6;

    const float4* o4a = (const float4*)(outp + (size_t)r0 * HW) + wave * QF4;
    const float4* t4a = (const float4*)(tgt  + (size_t)r0 * HW) + wave * QF4;
    const float4* o4b = (const float4*)(outp + (size_t)r1 * HW) + wave * QF4;
    const float4* t4b = (const float4*)(tgt  + (size_t)r1 * HW) + wave * QF4;

    // 4-deep rotating ring, 18 consumption steps (9 per row), fully unrolled
    // so every ring index is compile-time constant. Prologue = steps 0..3
    // (all row 0).
    float4 ob[4], tb[4];
#pragma unroll
    for (int p = 0; p < 4; ++p) {
        ob[p] = o4a[lane + p * 64];
        tb[p] = t4a[lane + p * 64];
    }

    float acc0 = 0.f, acc1 = 0.f;
#pragma unroll
    for (int s = 0; s < 18; ++s) {
        const float4 o = ob[s & 3];
        const float4 t = tb[s & 3];
        // Refill the slot just consumed with load for step s+4 (crosses the
        // row boundary without any drain; vmcnt stays counted, never 0).
        if (s + 4 < 18) {
            const int s2 = s + 4;
            if (s2 < 9) {
                ob[s & 3] = o4a[lane + s2 * 64];
                tb[s & 3] = t4a[lane + s2 * 64];
            } else {
                ob[s & 3] = o4b[lane + (s2 - 9) * 64];
                tb[s & 3] = t4b[lane + (s2 - 9) * 64];
            }
        }
        float d;
        float* acc = (s < 9) ? &acc0 : &acc1;   // compile-time select (unrolled)
        d = o.x - t.x; *acc = fmaf(d, d, *acc);
        d = o.y - t.y; *acc = fmaf(d, d, *acc);
        d = o.z - t.z; *acc = fmaf(d, d, *acc);
        d = o.w - t.w; *acc = fmaf(d, d, *acc);

        if (s == 8) {
            // Row 0 done for this wave: reduce + store while row-1 loads are
            // in flight. No barrier — per-wave partial, combined in k2.
            float r = acc0;
#pragma unroll
            for (int off = 32; off > 0; off >>= 1)
                r += __shfl_down(r, off, 64);
            if (lane == 0) pw[r0 * 4 + wave] = r;   // raw partial SSD
        }
    }

    // Row 1 reduce + store.
    float r = acc1;
#pragma unroll
    for (int off = 32; off > 0; off >>= 1)
        r += __shfl_down(r, off, 64);
    if (lane == 0) pw[r1 * 4 + wave] = r;
}

// Kernel 2: sum 4 wave-partials per row, apply w^2/HW, top-8-of-17, batch
// mean. 1 block, 128 threads. ~35 KB reads: measured-free vs the ~114us
// fixed harness residue (R4 proved removing k2 doesn't shrink the residue).
__global__ __launch_bounds__(128) void ohkm_reduce(
    const float* __restrict__ pw, const float* __restrict__ tw,
    float* __restrict__ result)
{
    const int b = threadIdx.x;   // 0..127
    float v[KJ];
#pragma unroll
    for (int k = 0; k < KJ; ++k) {
        const int r = b * KJ + k;
        const float s4 = pw[r * 4] + pw[r * 4 + 1] + pw[r * 4 + 2] + pw[r * 4 + 3];
        const float w  = tw[r];
        v[k] = s4 * w * w * (1.0f / (float)HW);
    }

    float s = 0.f;
#pragma unroll
    for (int t = 0; t < TOPK; ++t) {
        float m = v[0];
#pragma unroll
        for (int k = 1; k < KJ; ++k) m = fmaxf(m, v[k]);
        s += m;
        // remove exactly the FIRST element equal to m (tie-safe top_k semantics)
        bool removed = false;
#pragma unroll
        for (int k = 0; k < KJ; ++k) {
            const bool hit = (!removed) && (v[k] == m);
            v[k] = hit ? -INFINITY : v[k];
            removed = removed || hit;
        }
    }

    // 128 threads = 2 waves
#pragma unroll
    for (int off = 32; off > 0; off >>= 1)
        s += __shfl_down(s, off, 64);

    __shared__ float smem[2];
    if ((b & 63) == 0) smem[b >> 6] = s;
    __syncthreads();
    if (b == 0)
        result[0] = (smem[0] + smem[1]) * (1.0f / (float)(BATCH * TOPK));
}

extern "C" void kernel_launch(void* const* d_in, const int* in_sizes, int n_in,
                              void* d_out, int out_size, void* d_ws, size_t ws_size,
                              hipStream_t stream) {
    const float* outp = (const float*)d_in[0];   // [128,17,96,96]
    const float* tgt  = (const float*)d_in[1];   // [128,17,96,96]
    const float* tw   = (const float*)d_in[2];   // [128,17,1]
    float* result = (float*)d_out;               // scalar
    float* pw = (float*)d_ws;                    // [NROW*4] per-wave partials

    per_joint_partial<<<NBLK, 256, 0, stream>>>(outp, tgt, pw);
    ohkm_reduce<<<1, 128, 0, stream>>>(pw, tw, result);
}

// Round 8
// 163.535 us; speedup vs baseline: 1.1089x; 1.1089x over previous
//
#include <hip/hip_runtime.h>
#include <math.h>

#define HW     9216
#define KJ     17
#define BATCH  128
#define TOPK   8
#define NROW   (BATCH * KJ)      // 2176
#define CHUNK  3                 // chunk-blocks per row
#define CFLOAT (HW / CHUNK)      // 3072 floats per chunk (12 KB, f4-aligned)

typedef float f32x4 __attribute__((ext_vector_type(4)));  // clang vector:
// __builtin_nontemporal_load rejects HIP_vector_type (class) pointers.

// R7b: R5 structure (best samples 58.1us) + NONTEMPORAL loads. Theory: six
// structural variants {ILP 2..18, occ 31-58%, grid 1088..6528, +-barriers}
// all pin at 160MB/60us = 2.67 TB/s, and L3-resident replays run the SAME
// time -> limiter is the shared L2-miss/fabric path, not HBM, not wave MLP
// (R3 held 13x the in-flight bytes needed). Last untested mechanism:
// stream-once data ALLOCATES into L2+L3 on every fill; 160MB of fill-writes
// contend with demand reads on the same fabric/banks (explains replay
// non-speedup: L3 read-hits contend with L2-fill writes identically).
// nt policy = no-allocate/evict-first, removes the fill component.
// A/B vs R5: only the load policy changes.
__global__ __launch_bounds__(256, 6) void per_joint_partial(
    const float* __restrict__ outp, const float* __restrict__ tgt,
    float* __restrict__ pj3)
{
    const int g   = blockIdx.x;          // row * CHUNK + c
    const int row = g / CHUNK;
    const int c   = g - row * CHUNK;
    const size_t base = (size_t)row * HW + (size_t)c * CFLOAT;
    const f32x4* o4 = (const f32x4*)(outp + base);
    const f32x4* t4 = (const f32x4*)(tgt  + base);
    const int tid = threadIdx.x;

    // 3 float4 per tensor per thread — all 6 loads issued up front, nt policy.
    f32x4 o0 = __builtin_nontemporal_load(o4 + tid);
    f32x4 t0 = __builtin_nontemporal_load(t4 + tid);
    f32x4 o1 = __builtin_nontemporal_load(o4 + tid + 256);
    f32x4 t1 = __builtin_nontemporal_load(t4 + tid + 256);
    f32x4 o2 = __builtin_nontemporal_load(o4 + tid + 512);
    f32x4 t2 = __builtin_nontemporal_load(t4 + tid + 512);

    float acc = 0.f;
    float d;
    d = o0.x - t0.x; acc = fmaf(d, d, acc);
    d = o0.y - t0.y; acc = fmaf(d, d, acc);
    d = o0.z - t0.z; acc = fmaf(d, d, acc);
    d = o0.w - t0.w; acc = fmaf(d, d, acc);
    d = o1.x - t1.x; acc = fmaf(d, d, acc);
    d = o1.y - t1.y; acc = fmaf(d, d, acc);
    d = o1.z - t1.z; acc = fmaf(d, d, acc);
    d = o1.w - t1.w; acc = fmaf(d, d, acc);
    d = o2.x - t2.x; acc = fmaf(d, d, acc);
    d = o2.y - t2.y; acc = fmaf(d, d, acc);
    d = o2.z - t2.z; acc = fmaf(d, d, acc);
    d = o2.w - t2.w; acc = fmaf(d, d, acc);

    // wave64 shuffle reduce
#pragma unroll
    for (int off = 32; off > 0; off >>= 1)
        acc += __shfl_down(acc, off, 64);

    __shared__ float smem[4];
    if ((tid & 63) == 0) smem[tid >> 6] = acc;
    __syncthreads();
    if (tid == 0)
        pj3[g] = smem[0] + smem[1] + smem[2] + smem[3];   // raw partial SSD
}

// Kernel 2: sum 3 partials per row, apply w^2/HW, top-8-of-17, batch mean.
// 1 block, 128 threads. ~26 KB reads: measured-free vs the ~114us fixed
// harness residue (R4 proved removing k2 doesn't shrink the residue).
__global__ __launch_bounds__(128) void ohkm_reduce(
    const float* __restrict__ pj3, const float* __restrict__ tw,
    float* __restrict__ result)
{
    const int b = threadIdx.x;   // 0..127
    float v[KJ];
#pragma unroll
    for (int k = 0; k < KJ; ++k) {
        const int r = b * KJ + k;
        const float s3 = pj3[r * CHUNK] + pj3[r * CHUNK + 1] + pj3[r * CHUNK + 2];
        const float w  = tw[r];
        v[k] = s3 * w * w * (1.0f / (float)HW);
    }

    float s = 0.f;
#pragma unroll
    for (int t = 0; t < TOPK; ++t) {
        float m = v[0];
#pragma unroll
        for (int k = 1; k < KJ; ++k) m = fmaxf(m, v[k]);
        s += m;
        // remove exactly the FIRST element equal to m (tie-safe top_k semantics)
        bool removed = false;
#pragma unroll
        for (int k = 0; k < KJ; ++k) {
            const bool hit = (!removed) && (v[k] == m);
            v[k] = hit ? -INFINITY : v[k];
            removed = removed || hit;
        }
    }

    // 128 threads = 2 waves
#pragma unroll
    for (int off = 32; off > 0; off >>= 1)
        s += __shfl_down(s, off, 64);

    __shared__ float smem[2];
    if ((b & 63) == 0) smem[b >> 6] = s;
    __syncthreads();
    if (b == 0)
        result[0] = (smem[0] + smem[1]) * (1.0f / (float)(BATCH * TOPK));
}

extern "C" void kernel_launch(void* const* d_in, const int* in_sizes, int n_in,
                              void* d_out, int out_size, void* d_ws, size_t ws_size,
                              hipStream_t stream) {
    const float* outp = (const float*)d_in[0];   // [128,17,96,96]
    const float* tgt  = (const float*)d_in[1];   // [128,17,96,96]
    const float* tw   = (const float*)d_in[2];   // [128,17,1]
    float* result = (float*)d_out;               // scalar
    float* pj3 = (float*)d_ws;                   // [NROW*CHUNK] partial SSDs

    per_joint_partial<<<NROW * CHUNK, 256, 0, stream>>>(outp, tgt, pj3);
    ohkm_reduce<<<1, 128, 0, stream>>>(pj3, tw, result);
}